// Round 2
// baseline (400.564 us; speedup 1.0000x reference)
//
#include <hip/hip_runtime.h>
#include <math.h>

#define ALPHA 0.1f

// ---------------------------------------------------------------------------
// Kernel 1: per-token smoothing parameters (off, src) + lensum.
// Single block of 256 threads; N tokens (N = B*T, 4096 here).
// Faithful to the reference:
//   eos      = (t == 1)
//   seg_id   = exclusive count of eos before n   (cumsum(eos) - eos)
//   is_start = (n == 0) || (t[n-1] == 1)
//   forth    = is_start ? N-1 : t[n-1]
//   need     = matric[forth, t[n]]
//   sm       = 1 - (1-ALPHA)^(1/(len[seg]+1))
//   off      = sm*need/(V-1);  src = 1 - off*V
// ---------------------------------------------------------------------------
__global__ __launch_bounds__(256) void token_params_kernel(
    const int* __restrict__ t, const float* __restrict__ matric,
    const int* __restrict__ lens, float* __restrict__ offv,
    float* __restrict__ srcv, float* __restrict__ lensum,
    int N, int V, int B)
{
    __shared__ int cnts[256];
    const int tid = threadIdx.x;
    const int chunk = (N + 255) / 256;
    const int c0 = tid * chunk;
    const int c1 = min(c0 + chunk, N);

    // per-thread eos count
    int cnt = 0;
    for (int n = c0; n < c1; ++n) cnt += (t[n] == 1);
    cnts[tid] = cnt;
    __syncthreads();

    // Hillis-Steele inclusive scan over 256 thread counts
    for (int d = 1; d < 256; d <<= 1) {
        int v = 0;
        if (tid >= d) v = cnts[tid - d];
        __syncthreads();
        if (tid >= d) cnts[tid] += v;
        __syncthreads();
    }
    int run = (tid == 0) ? 0 : cnts[tid - 1];  // exclusive base for this chunk

    const float inv_vm1 = 1.0f / (float)(V - 1);
    for (int n = c0; n < c1; ++n) {
        const int tn = t[n];
        const bool e = (tn == 1);
        int seg = run;                 // exclusive eos count before n
        if (e) run += 1;
        seg = min(seg, B - 1);         // jax clamps OOB gather indices
        if (seg < 0) seg = 0;

        const int prev = (n == 0) ? 0 : t[n - 1];
        const bool is_start = (n == 0) || (prev == 1);
        const int forth = is_start ? (N - 1) : prev;

        const float need = matric[(size_t)forth * V + tn];
        const float len = (float)(lens[seg] + 1);
        const float sm = 1.0f - powf(1.0f - ALPHA, 1.0f / len);
        const float off = sm * need * inv_vm1;
        offv[n] = off;
        srcv[n] = 1.0f - off * (float)V;
    }

    if (tid == 0) {
        float ls = 0.f;
        for (int b = 0; b < B; ++b) ls += (float)(lens[b] + 1);
        lensum[0] = ls;
    }
}

// ---------------------------------------------------------------------------
// (m, s) online-softmax combine
// ---------------------------------------------------------------------------
__device__ __forceinline__ void combine_ms(float& m, float& s, float om, float os) {
    float nm = fmaxf(m, om);
    s = s * __expf(m - nm) + os * __expf(om - nm);
    m = nm;
}

__device__ __forceinline__ void row_epilogue(
    float M, float Z, float Sx, float xt,
    const float* __restrict__ offv, const float* __restrict__ srcv,
    float* __restrict__ rowkl, int row, int V)
{
    const float logZ = logf(Z) + M;
    const float lpt = xt - logZ;                 // logp[target]
    const float S = Sx - (float)V * logZ;        // sum_v logp
    const float o = offv[row];
    const float sr = srcv[row];
    const float xlo = (o > 0.f) ? o * logf(o) : 0.f;
    const float xls = (sr > 0.f) ? sr * logf(sr) : 0.f;
    rowkl[row] = (float)(V - 1) * xlo + xls - (o * (S - lpt) + sr * lpt);
}

// ---------------------------------------------------------------------------
// Kernel 2 (specialized): one block per row, V = NV4*256*4 floats.
// Single global pass: row held in registers (NV4 float4 per thread).
// ---------------------------------------------------------------------------
template <int NV4>
__global__ __launch_bounds__(256) void row_kl_kernel(
    const float* __restrict__ x, const int* __restrict__ t,
    const float* __restrict__ offv, const float* __restrict__ srcv,
    float* __restrict__ rowkl, int V)
{
    const int row = blockIdx.x;
    const int tid = threadIdx.x;
    const float4* xr = reinterpret_cast<const float4*>(x + (size_t)row * V);

    float4 v[NV4];
#pragma unroll
    for (int k = 0; k < NV4; ++k) v[k] = xr[tid + k * 256];

    const int tgt = t[row];
    float m = -INFINITY, sx = 0.f, xt_local = 0.f;
    bool have = false;
#pragma unroll
    for (int k = 0; k < NV4; ++k) {
        const float4 q = v[k];
        m = fmaxf(fmaxf(fmaxf(m, q.x), q.y), fmaxf(q.z, q.w));
        sx += (q.x + q.y) + (q.z + q.w);
        const int c = tgt - 4 * (tid + k * 256);
        if (c >= 0 && c < 4) {
            xt_local = (c == 0) ? q.x : (c == 1) ? q.y : (c == 2) ? q.z : q.w;
            have = true;
        }
    }
    float s = 0.f;
#pragma unroll
    for (int k = 0; k < NV4; ++k) {
        const float4 q = v[k];
        s += (__expf(q.x - m) + __expf(q.y - m)) + (__expf(q.z - m) + __expf(q.w - m));
    }

    __shared__ float sm_m[4], sm_s[4], sm_sx[4], sm_xt;
    if (have) sm_xt = xt_local;

    // wave64 butterfly reduce
    for (int d = 1; d < 64; d <<= 1) {
        float om = __shfl_xor(m, d);
        float os = __shfl_xor(s, d);
        float osx = __shfl_xor(sx, d);
        combine_ms(m, s, om, os);
        sx += osx;
    }
    const int lane = tid & 63, wid = tid >> 6;
    if (lane == 0) { sm_m[wid] = m; sm_s[wid] = s; sm_sx[wid] = sx; }
    __syncthreads();
    if (tid == 0) {
        for (int w = 1; w < 4; ++w) { combine_ms(m, s, sm_m[w], sm_s[w]); sx += sm_sx[w]; }
        row_epilogue(m, s, sx, sm_xt, offv, srcv, rowkl, row, V);
    }
}

// ---------------------------------------------------------------------------
// Kernel 2 (generic fallback, any V): two-pass over the row.
// ---------------------------------------------------------------------------
__global__ __launch_bounds__(256) void row_kl_generic(
    const float* __restrict__ x, const int* __restrict__ t,
    const float* __restrict__ offv, const float* __restrict__ srcv,
    float* __restrict__ rowkl, int V)
{
    const int row = blockIdx.x;
    const int tid = threadIdx.x;
    const float* xr = x + (size_t)row * V;
    const int tgt = t[row];

    float m = -INFINITY, sx = 0.f, xt = 0.f;
    bool have = false;
    for (int i = tid; i < V; i += 256) {
        const float q = xr[i];
        m = fmaxf(m, q);
        sx += q;
        if (i == tgt) { xt = q; have = true; }
    }
    __shared__ float shm[4], shs[4], shsx[4], shxt, shM;
    if (have) shxt = xt;
    for (int d = 1; d < 64; d <<= 1) {
        m = fmaxf(m, __shfl_xor(m, d));
        sx += __shfl_xor(sx, d);
    }
    const int lane = tid & 63, wid = tid >> 6;
    if (lane == 0) { shm[wid] = m; shsx[wid] = sx; }
    __syncthreads();
    if (tid == 0) {
        float M = shm[0];
        for (int w = 1; w < 4; ++w) M = fmaxf(M, shm[w]);
        shM = M;
    }
    __syncthreads();
    const float M = shM;
    float s = 0.f;
    for (int i = tid; i < V; i += 256) s += __expf(xr[i] - M);
    for (int d = 1; d < 64; d <<= 1) s += __shfl_xor(s, d);
    if (lane == 0) shs[wid] = s;
    __syncthreads();
    if (tid == 0) {
        const float Z = shs[0] + shs[1] + shs[2] + shs[3];
        const float SX = shsx[0] + shsx[1] + shsx[2] + shsx[3];
        row_epilogue(M, Z, SX, shxt, offv, srcv, rowkl, row, V);
    }
}

// ---------------------------------------------------------------------------
// Kernel 3: final reduction + normalization
// ---------------------------------------------------------------------------
__global__ __launch_bounds__(256) void finalize_kernel(
    const float* __restrict__ rowkl, const float* __restrict__ lensum,
    float* __restrict__ out, int N)
{
    __shared__ float sh[4];
    float a = 0.f;
    for (int i = threadIdx.x; i < N; i += 256) a += rowkl[i];
    for (int d = 1; d < 64; d <<= 1) a += __shfl_xor(a, d);
    const int lane = threadIdx.x & 63, wid = threadIdx.x >> 6;
    if (lane == 0) sh[wid] = a;
    __syncthreads();
    if (threadIdx.x == 0) {
        out[0] = (sh[0] + sh[1] + sh[2] + sh[3]) / lensum[0];
    }
}

extern "C" void kernel_launch(void* const* d_in, const int* in_sizes, int n_in,
                              void* d_out, int out_size, void* d_ws, size_t ws_size,
                              hipStream_t stream) {
    const float* x      = (const float*)d_in[0];   // [B,T,V] logits
    const float* matric = (const float*)d_in[1];   // [V,V]
    const int*   tgts   = (const int*)d_in[2];     // [B,T]
    const int*   lens   = (const int*)d_in[3];     // [B]

    const int N = in_sizes[2];               // B*T
    const int B = in_sizes[3];
    const int V = in_sizes[0] / in_sizes[2];

    float* ws     = (float*)d_ws;
    float* rowkl  = ws;            // N floats
    float* offv   = ws + N;        // N floats
    float* srcv   = ws + 2 * N;    // N floats
    float* lensum = ws + 3 * N;    // 1 float

    token_params_kernel<<<1, 256, 0, stream>>>(tgts, matric, lens, offv, srcv,
                                               lensum, N, V, B);
    if (V == 8 * 256 * 4) {
        row_kl_kernel<8><<<N, 256, 0, stream>>>(x, tgts, offv, srcv, rowkl, V);
    } else {
        row_kl_generic<<<N, 256, 0, stream>>>(x, tgts, offv, srcv, rowkl, V);
    }
    finalize_kernel<<<1, 256, 0, stream>>>(rowkl, lensum, (float*)d_out, N);
}

// Round 4
// 396.522 us; speedup vs baseline: 1.0102x; 1.0102x over previous
//
#include <hip/hip_runtime.h>
#include <math.h>

#define ALPHA 0.1f

// ---------------------------------------------------------------------------
// Tiny zeroing kernel (graph-capture-safe replacement for hipMemsetAsync).
// ---------------------------------------------------------------------------
__global__ void zero_out_kernel(float* __restrict__ out) {
    out[0] = 0.0f;
}

// ---------------------------------------------------------------------------
// (m, s) online-softmax combine
// ---------------------------------------------------------------------------
__device__ __forceinline__ void combine_ms(float& m, float& s, float om, float os) {
    float nm = fmaxf(m, om);
    s = s * __expf(m - nm) + os * __expf(om - nm);
    m = nm;
}

// ---------------------------------------------------------------------------
// Fully fused kernel (V == NV4*256*4): one block per row.
//   1. block counts EOS in t[0..row) -> seg id (t is 16 KiB, L1-hot)
//   2. thread 0 derives off/src from matric gather + powf, and lensum
//   3. single-pass row softmax stats from registers (NV4 float4 / thread)
//   4. thread 0 computes closed-form row KL, atomicAdd into out
// out is zeroed by zero_out_kernel first.
//
// Closed form per row (weight = off everywhere, src at target):
//   logZ  = max + log(sum exp(x-max))
//   logp_t= x[t] - logZ ; sum_v logp = Sx - V*logZ
//   kl    = (V-1)*xlogy(off,off) + xlogy(src,src)
//           - off*(sum_v logp - logp_t) - src*logp_t
// ---------------------------------------------------------------------------
template <int NV4>
__global__ __launch_bounds__(256) void fused_row_kl(
    const float* __restrict__ x, const float* __restrict__ matric,
    const int* __restrict__ t, const int* __restrict__ lens,
    float* __restrict__ out, int N, int V, int B)
{
    const int row = blockIdx.x;
    const int tid = threadIdx.x;

    // Issue the row loads first so HBM latency hides under the token scan.
    const float4* xr = reinterpret_cast<const float4*>(x + (size_t)row * V);
    float4 v[NV4];
#pragma unroll
    for (int k = 0; k < NV4; ++k) v[k] = xr[tid + k * 256];

    // ---- segment id: EOS count strictly before this row ----
    int cnt = 0;
    for (int i = tid; i < row; i += 256) cnt += (t[i] == 1);
    for (int d = 1; d < 64; d <<= 1) cnt += __shfl_xor(cnt, d);

    __shared__ int scnt[4];
    __shared__ float sh_off, sh_src, sh_ls, sh_xt;
    __shared__ float sm_m[4], sm_s[4], sm_sx[4];
    const int lane = tid & 63, wid = tid >> 6;
    if (lane == 0) scnt[wid] = cnt;
    __syncthreads();

    if (tid == 0) {
        int seg = scnt[0] + scnt[1] + scnt[2] + scnt[3];
        seg = min(max(seg, 0), B - 1);           // jax clamps OOB gathers
        const int tn = t[row];
        const int prev = (row == 0) ? 0 : t[row - 1];
        const bool is_start = (row == 0) || (prev == 1);
        const int forth = is_start ? (N - 1) : prev;
        const float need = matric[(size_t)forth * V + tn];
        const float len = (float)(lens[seg] + 1);
        const float sm = 1.0f - powf(1.0f - ALPHA, 1.0f / len);
        const float off = sm * need / (float)(V - 1);
        sh_off = off;
        sh_src = 1.0f - off * (float)V;
        float ls = 0.f;
        for (int b = 0; b < B; ++b) ls += (float)(lens[b] + 1);
        sh_ls = ls;
    }

    // ---- row statistics: max, sum(x), x[target] ----
    const int tgt = t[row];
    float m = -INFINITY, sx = 0.f, xt_local = 0.f;
    bool have = false;
#pragma unroll
    for (int k = 0; k < NV4; ++k) {
        const float4 q = v[k];
        m = fmaxf(fmaxf(fmaxf(m, q.x), q.y), fmaxf(q.z, q.w));
        sx += (q.x + q.y) + (q.z + q.w);
        const int c = tgt - 4 * (tid + k * 256);
        if (c >= 0 && c < 4) {
            xt_local = (c == 0) ? q.x : (c == 1) ? q.y : (c == 2) ? q.z : q.w;
            have = true;
        }
    }
    if (have) sh_xt = xt_local;

    float s = 0.f;
#pragma unroll
    for (int k = 0; k < NV4; ++k) {
        const float4 q = v[k];
        s += (__expf(q.x - m) + __expf(q.y - m)) + (__expf(q.z - m) + __expf(q.w - m));
    }

    // wave64 butterfly reduce (m,s online-combine; sx plain sum)
    for (int d = 1; d < 64; d <<= 1) {
        float om = __shfl_xor(m, d);
        float os = __shfl_xor(s, d);
        float osx = __shfl_xor(sx, d);
        combine_ms(m, s, om, os);
        sx += osx;
    }
    if (lane == 0) { sm_m[wid] = m; sm_s[wid] = s; sm_sx[wid] = sx; }
    __syncthreads();

    if (tid == 0) {
        for (int w = 1; w < 4; ++w) { combine_ms(m, s, sm_m[w], sm_s[w]); sx += sm_sx[w]; }
        const float logZ = logf(s) + m;
        const float lpt = sh_xt - logZ;             // logp[target]
        const float S = sx - (float)V * logZ;       // sum_v logp
        const float o = sh_off;
        const float sr = sh_src;
        const float xlo = (o > 0.f) ? o * logf(o) : 0.f;
        const float xls = (sr > 0.f) ? sr * logf(sr) : 0.f;
        const float kl = (float)(V - 1) * xlo + xls - (o * (S - lpt) + sr * lpt);
        atomicAdd(out, kl / sh_ls);
    }
}

// ---------------------------------------------------------------------------
// Generic fallback path (any V): 3-kernel pipeline through workspace.
// ---------------------------------------------------------------------------
__global__ __launch_bounds__(256) void token_params_kernel(
    const int* __restrict__ t, const float* __restrict__ matric,
    const int* __restrict__ lens, float* __restrict__ offv,
    float* __restrict__ srcv, float* __restrict__ lensum,
    int N, int V, int B)
{
    __shared__ int cnts[256];
    const int tid = threadIdx.x;
    const int chunk = (N + 255) / 256;
    const int c0 = tid * chunk;
    const int c1 = min(c0 + chunk, N);

    int cnt = 0;
    for (int n = c0; n < c1; ++n) cnt += (t[n] == 1);
    cnts[tid] = cnt;
    __syncthreads();
    for (int d = 1; d < 256; d <<= 1) {
        int v = 0;
        if (tid >= d) v = cnts[tid - d];
        __syncthreads();
        if (tid >= d) cnts[tid] += v;
        __syncthreads();
    }
    int run = (tid == 0) ? 0 : cnts[tid - 1];

    const float inv_vm1 = 1.0f / (float)(V - 1);
    for (int n = c0; n < c1; ++n) {
        const int tn = t[n];
        int seg = min(max(run, 0), B - 1);
        if (tn == 1) run += 1;
        const int prev = (n == 0) ? 0 : t[n - 1];
        const bool is_start = (n == 0) || (prev == 1);
        const int forth = is_start ? (N - 1) : prev;
        const float need = matric[(size_t)forth * V + tn];
        const float len = (float)(lens[seg] + 1);
        const float sm = 1.0f - powf(1.0f - ALPHA, 1.0f / len);
        const float off = sm * need * inv_vm1;
        offv[n] = off;
        srcv[n] = 1.0f - off * (float)V;
    }
    if (tid == 0) {
        float ls = 0.f;
        for (int b = 0; b < B; ++b) ls += (float)(lens[b] + 1);
        lensum[0] = ls;
    }
}

__global__ __launch_bounds__(256) void row_kl_generic(
    const float* __restrict__ x, const int* __restrict__ t,
    const float* __restrict__ offv, const float* __restrict__ srcv,
    float* __restrict__ rowkl, int V)
{
    const int row = blockIdx.x;
    const int tid = threadIdx.x;
    const float* xr = x + (size_t)row * V;
    const int tgt = t[row];

    float m = -INFINITY, sx = 0.f, xt = 0.f;
    bool have = false;
    for (int i = tid; i < V; i += 256) {
        const float q = xr[i];
        m = fmaxf(m, q);
        sx += q;
        if (i == tgt) { xt = q; have = true; }
    }
    __shared__ float shm[4], shs[4], shsx[4], shxt, shM;
    if (have) shxt = xt;
    for (int d = 1; d < 64; d <<= 1) {
        m = fmaxf(m, __shfl_xor(m, d));
        sx += __shfl_xor(sx, d);
    }
    const int lane = tid & 63, wid = tid >> 6;
    if (lane == 0) { shm[wid] = m; shsx[wid] = sx; }
    __syncthreads();
    if (tid == 0) {
        float M = shm[0];
        for (int w = 1; w < 4; ++w) M = fmaxf(M, shm[w]);
        shM = M;
    }
    __syncthreads();
    const float M = shM;
    float s = 0.f;
    for (int i = tid; i < V; i += 256) s += __expf(xr[i] - M);
    for (int d = 1; d < 64; d <<= 1) s += __shfl_xor(s, d);
    if (lane == 0) shs[wid] = s;
    __syncthreads();
    if (tid == 0) {
        const float Z = shs[0] + shs[1] + shs[2] + shs[3];
        const float SX = shsx[0] + shsx[1] + shsx[2] + shsx[3];
        const float logZ = logf(Z) + M;
        const float lpt = shxt - logZ;
        const float S = SX - (float)V * logZ;
        const float o = offv[row];
        const float sr = srcv[row];
        const float xlo = (o > 0.f) ? o * logf(o) : 0.f;
        const float xls = (sr > 0.f) ? sr * logf(sr) : 0.f;
        rowkl[row] = (float)(V - 1) * xlo + xls - (o * (S - lpt) + sr * lpt);
    }
}

__global__ __launch_bounds__(256) void finalize_kernel(
    const float* __restrict__ rowkl, const float* __restrict__ lensum,
    float* __restrict__ out, int N)
{
    __shared__ float sh[4];
    float a = 0.f;
    for (int i = threadIdx.x; i < N; i += 256) a += rowkl[i];
    for (int d = 1; d < 64; d <<= 1) a += __shfl_xor(a, d);
    const int lane = threadIdx.x & 63, wid = threadIdx.x >> 6;
    if (lane == 0) sh[wid] = a;
    __syncthreads();
    if (threadIdx.x == 0) {
        out[0] = (sh[0] + sh[1] + sh[2] + sh[3]) / lensum[0];
    }
}

extern "C" void kernel_launch(void* const* d_in, const int* in_sizes, int n_in,
                              void* d_out, int out_size, void* d_ws, size_t ws_size,
                              hipStream_t stream) {
    const float* x      = (const float*)d_in[0];   // [B,T,V] logits
    const float* matric = (const float*)d_in[1];   // [V,V]
    const int*   tgts   = (const int*)d_in[2];     // [B,T]
    const int*   lens   = (const int*)d_in[3];     // [B]

    const int N = in_sizes[2];               // B*T
    const int B = in_sizes[3];
    const int V = in_sizes[0] / in_sizes[2];

    if (V == 8 * 256 * 4) {
        // zero the scalar accumulator, then one fused kernel
        zero_out_kernel<<<1, 1, 0, stream>>>((float*)d_out);
        fused_row_kl<8><<<N, 256, 0, stream>>>(x, matric, tgts, lens,
                                               (float*)d_out, N, V, B);
    } else {
        float* ws     = (float*)d_ws;
        float* rowkl  = ws;
        float* offv   = ws + N;
        float* srcv   = ws + 2 * N;
        float* lensum = ws + 3 * N;
        token_params_kernel<<<1, 256, 0, stream>>>(tgts, matric, lens, offv, srcv,
                                                   lensum, N, V, B);
        row_kl_generic<<<N, 256, 0, stream>>>(x, tgts, offv, srcv, rowkl, V);
        finalize_kernel<<<1, 256, 0, stream>>>(rowkl, lensum, (float*)d_out, N);
    }
}